// Round 9
// baseline (243.352 us; speedup 1.0000x reference)
//
#include <hip/hip_runtime.h>

#define B_ 4
#define S_ 2048
#define D_ 1024
#define H_ 16
#define HD_ 64

typedef __attribute__((ext_vector_type(8))) short bf16x8;
typedef __attribute__((ext_vector_type(4))) float f32x4;
typedef __attribute__((ext_vector_type(4))) unsigned u32x4;

__device__ __forceinline__ short f2bf(float f) {
  unsigned u = __builtin_bit_cast(unsigned, f);
  u += 0x7fffu + ((u >> 16) & 1u);   // RNE
  return (short)(u >> 16);
}

// HW packed f32x2 -> bf16x2 (RNE); no builtin on gfx950 -> inline asm (T12)
__device__ __forceinline__ unsigned cvtpk(float a, float b) {
  unsigned r;
  asm("v_cvt_pk_bf16_f32 %0, %1, %2" : "=v"(r) : "v"(a), "v"(b));
  return r;
}

__device__ __forceinline__ void gload_lds16(const void* g, void* l) {
  __builtin_amdgcn_global_load_lds((const __attribute__((address_space(1))) void*)g,
                                   (__attribute__((address_space(3))) void*)l, 16, 0, 0);
}

// swizzled LDS bf16x8 read from a [rows][64] bf16 tile (128B rows, T2 XOR swizzle)
__device__ __forceinline__ bf16x8 ldsw8(const short* base, int row, int colb) {
  const int off = (row * 128 + colb) ^ ((row & 7) << 4);
  return *(const bf16x8*)((const char*)base + off);
}

// pair-row swizzle for 64B-row bf16 tiles ([rows][32 shorts]): logical (row, cbyte)
// -> byte offset. Per-16-lane slot = ((row&1)*4+lq) ^ ((row>>1)&7): all 8 slots x2 = free.
__device__ __forceinline__ int bpr_off(int row, int cbyte) {
  return ((row >> 1) << 7) + ((((row & 1) << 6) + cbyte) ^ (((row >> 1) & 7) << 4));
}

#define MFMA16(a, b, c) __builtin_amdgcn_mfma_f32_16x16x32_bf16((a), (b), (c), 0, 0, 0)
#define PBAR()   asm volatile("s_barrier" ::: "memory")
#define LGKM0()  do { asm volatile("s_waitcnt lgkmcnt(0)" ::: "memory"); \
                      __builtin_amdgcn_sched_barrier(0); } while (0)
#define VM0()    asm volatile("s_waitcnt vmcnt(0)" ::: "memory")

// ---------------- 4x W [K][N] f32 -> Wt [N][K] bf16, one dispatch ----------------
__global__ void transpose_cast_w4(const float* __restrict__ W0, const float* __restrict__ W1,
                                  const float* __restrict__ W2, const float* __restrict__ W3,
                                  short* __restrict__ T0, short* __restrict__ T1,
                                  short* __restrict__ T2, short* __restrict__ T3) {
  __shared__ float tile[32][33];
  const int z = blockIdx.z;
  const float* W = z == 0 ? W0 : z == 1 ? W1 : z == 2 ? W2 : W3;
  short* Wt = z == 0 ? T0 : z == 1 ? T1 : z == 2 ? T2 : T3;
  const int n0 = blockIdx.x * 32, k0 = blockIdx.y * 32;
  const int tx = threadIdx.x, ty = threadIdx.y;  // 32 x 8
  #pragma unroll
  for (int i = ty; i < 32; i += 8)
    tile[i][tx] = W[(size_t)(k0 + i) * 1024 + n0 + tx];
  __syncthreads();
  #pragma unroll
  for (int i = ty; i < 32; i += 8)
    Wt[(size_t)(n0 + i) * 1024 + k0 + tx] = f2bf(tile[tx][i]);
}

// -------- 8-phase 256x256x64 QKV GEMM, fused f32->bf16 cast (T2+T3+T4+T5) --------
// 512 threads = 8 waves (2M x 4N); per-wave 128x64 output (acc[8][4]).
// LDS 160KB: A f32 double-buffered 2x64KB (XOR-swizzled 256B rows) +
//            B bf16 SINGLE buffer 32KB (XOR-swizzled 128B rows).
// B is fully consumed into registers at phase 0 -> B(t+1) staged at phase 1 into
// the (now dead) single buffer; A(t+1) staged at phases 1-2 into the dead dbuf
// half; tile entry = vmcnt(0)+s_barrier (all loads >=2 phases old).
// A-fragments read as f32 pairs + v_cvt_pk_bf16_f32 (no extra VGPR pressure).
// z==0: Q out [B][H][S][HD]*qscale; z==1: K out; z==2: V out [B][H][HD][S].
__global__ __launch_bounds__(512, 2) void gemm8(const float* __restrict__ Aq,
                                                const float* __restrict__ Ak,
                                                const float* __restrict__ Av,
                                                const short* __restrict__ Bq,
                                                const short* __restrict__ Bk,
                                                const short* __restrict__ Bv,
                                                short* __restrict__ Oq,
                                                short* __restrict__ Ok,
                                                short* __restrict__ Ov,
                                                float qscale) {
  __shared__ __align__(16) float AsF[2][16384];   // 2 x 64KB f32
  __shared__ __align__(16) short BsS[16384];      // 32KB bf16 (single)
  const int z = blockIdx.z;
  const float* A = z == 0 ? Aq : z == 1 ? Ak : Av;
  const short* Bt = z == 0 ? Bq : z == 1 ? Bk : Bv;
  short* outb = z == 0 ? Oq : z == 1 ? Ok : Ov;
  const float oscale = (z == 0) ? qscale : 1.0f;

  const int tid = threadIdx.x;
  const int l = tid & 63, w = tid >> 6;
  const int wm = w >> 2, wn = w & 3;                // 2M x 4N waves
  const int l15 = l & 15, lq = l >> 4;
  const int flat = blockIdx.x + (blockIdx.y << 2);  // grid (4, 32, 3)
  const int vid = (flat & 7) * 16 + (flat >> 3);    // XCD-grouped remap
  const int row0 = (vid >> 2) * 256;
  const int col0 = (vid & 3) * 256;

  f32x4 acc[8][4] = {};

  // B tile 256 rows x 64 bf16 (128B rows, XOR pre-swizzled source, rule 21)
  auto stageB = [&](int kt) {
    #pragma unroll
    for (int j = 0; j < 4; ++j) {
      const int o2 = w * 4096 + j * 1024 + l * 16;
      const int row = o2 >> 7;
      const int sc = (o2 & 127) ^ ((row & 7) << 4);
      gload_lds16((const char*)Bt + (size_t)(col0 + row) * 2048 + kt * 128 + sc,
                  (char*)BsS + o2);
    }
  };
  // A tile 256 rows x 64 f32 (256B rows, XOR pre-swizzled source); batch 0/1 = 4 loads each
  auto stageA = [&](int kt, int buf, int batch) {
    #pragma unroll
    for (int j = 0; j < 4; ++j) {
      const int o2 = w * 8192 + (batch * 4 + j) * 1024 + l * 16;
      const int row = o2 >> 8;
      const int sc = (o2 & 255) ^ ((row & 7) << 4);
      gload_lds16((const char*)A + (size_t)(row0 + row) * 4096 + kt * 256 + sc,
                  (char*)AsF[buf] + o2);
    }
  };
  // f32 A-fragment read + packed convert (rows 256B, same XOR swizzle)
  auto rdA = [&](const float* as, int R, int ks) -> bf16x8 {
    const int s = (R & 7) << 4;
    const int c0 = (ks * 128 + lq * 32) ^ s;
    const f32x4 g0 = *(const f32x4*)((const char*)as + R * 256 + c0);
    const f32x4 g1 = *(const f32x4*)((const char*)as + R * 256 + (c0 ^ 16));
    const u32x4 uu = {cvtpk(g0[0], g0[1]), cvtpk(g0[2], g0[3]),
                      cvtpk(g1[0], g1[1]), cvtpk(g1[2], g1[3])};
    return __builtin_bit_cast(bf16x8, uu);
  };

  // prologue: B(0) + A(0), full drain
  stageB(0);
  stageA(0, 0, 0);
  stageA(0, 0, 1);
  VM0();
  PBAR();

  for (int t = 0; t < 16; ++t) {
    const int c = t & 1, o = c ^ 1;
    const float* Ah = AsF[c];
    bf16x8 bfr[4][2];

    #pragma unroll
    for (int p = 0; p < 4; ++p) {
      // staging into dead-only regions (B dead after phase-0 barrier; AsF[o] dead)
      if (p == 1 && t + 1 < 16) { stageB(t + 1); stageA(t + 1, o, 0); }
      if (p == 2 && t + 1 < 16) stageA(t + 1, o, 1);

      if (p == 0) {
        #pragma unroll
        for (int nf = 0; nf < 4; ++nf)
          #pragma unroll
          for (int ks = 0; ks < 2; ++ks)
            bfr[nf][ks] = ldsw8(BsS, wn * 64 + nf * 16 + l15, ks * 64 + lq * 16);
      }
      const bf16x8 a00 = rdA(Ah, wm * 128 + (2 * p) * 16 + l15, 0);
      const bf16x8 a01 = rdA(Ah, wm * 128 + (2 * p) * 16 + l15, 1);
      const bf16x8 a10 = rdA(Ah, wm * 128 + (2 * p + 1) * 16 + l15, 0);
      const bf16x8 a11 = rdA(Ah, wm * 128 + (2 * p + 1) * 16 + l15, 1);

      LGKM0();
      __builtin_amdgcn_s_setprio(1);
      #pragma unroll
      for (int nf = 0; nf < 4; ++nf) {
        acc[2 * p][nf]     = MFMA16(a00, bfr[nf][0], acc[2 * p][nf]);
        acc[2 * p][nf]     = MFMA16(a01, bfr[nf][1], acc[2 * p][nf]);
        acc[2 * p + 1][nf] = MFMA16(a10, bfr[nf][0], acc[2 * p + 1][nf]);
        acc[2 * p + 1][nf] = MFMA16(a11, bfr[nf][1], acc[2 * p + 1][nf]);
      }
      __builtin_amdgcn_s_setprio(0);
      if (p < 3) PBAR();
    }
    // tile boundary: next tile's A/B staged loads must have landed for phase 0
    if (t + 1 < 16) { VM0(); PBAR(); }
  }

  // epilogue: C/D layout col=lane&15, row=(lane>>4)*4+reg
  #pragma unroll
  for (int mf = 0; mf < 8; ++mf) {
    #pragma unroll
    for (int nf = 0; nf < 4; ++nf) {
      #pragma unroll
      for (int r = 0; r < 4; ++r) {
        const int gr = row0 + wm * 128 + mf * 16 + lq * 4 + r;  // m = b*S + s
        const int gc = col0 + wn * 64 + nf * 16 + l15;          // n = h*64 + hd
        const float v = acc[mf][nf][r];
        const int b = gr >> 11, s = gr & 2047;
        const int h = gc >> 6, hd = gc & 63;
        if (z < 2)
          outb[(((size_t)(b * H_ + h)) * S_ + s) * HD_ + hd] = f2bf(v * oscale);
        else
          outb[(((size_t)(b * H_ + h)) * HD_ + hd) * S_ + s] = f2bf(v);
      }
    }
  }
}

// ---------------- O-projection GEMM (round-6 proven): f32 out = A_bf16 @ Wot^T + bias ----
__global__ __launch_bounds__(256) void gemm_o(const short* __restrict__ A,
                                              const short* __restrict__ Bt,
                                              float* __restrict__ outf,
                                              const float* __restrict__ bias) {
  __shared__ __align__(16) short As[2][128 * 32];
  __shared__ __align__(16) short Bs[2][128 * 32];
  const int tid = threadIdx.x;
  const int l = tid & 63;
  const int w = tid >> 6;
  const int wm = w >> 1, wn = w & 1;
  const int flat = blockIdx.x + (blockIdx.y << 3);
  const int xcd = flat & 7, t = flat >> 3;
  const int row0 = (xcd * 8 + (t & 7)) * 128;
  const int col0 = (t >> 3) * 128;
  const int l15 = l & 15, lq = l >> 4;

  f32x4 acc[4][4] = {};

  auto stage = [&](const short* src, int r0, int k0, short* lds) {
    #pragma unroll
    for (int i = 0; i < 2; i++) {
      const int o = w * 2048 + i * 1024 + l * 16;      // dest byte in 8KB tile
      const int row2 = o >> 7;
      const int ip = (o & 127) ^ ((row2 & 7) << 4);
      const int row = row2 * 2 + (ip >> 6);
      const int cb = ip & 63;
      gload_lds16((const char*)src + ((size_t)(r0 + row) * 1024 + k0) * 2 + cb,
                  (char*)lds + o);
    }
  };

  stage(A, row0, 0, As[0]);
  stage(Bt, col0, 0, Bs[0]);

  for (int kt = 0; kt < 32; ++kt) {
    __syncthreads();
    if (kt + 1 < 32) {
      stage(A, row0, (kt + 1) * 32, As[(kt + 1) & 1]);
      stage(Bt, col0, (kt + 1) * 32, Bs[(kt + 1) & 1]);
    }
    const short* as = As[kt & 1];
    const short* bs = Bs[kt & 1];
    bf16x8 af[4], bfv[4];
    #pragma unroll
    for (int mf = 0; mf < 4; mf++)
      af[mf] = *(const bf16x8*)((const char*)as + bpr_off(wm * 64 + mf * 16 + l15, lq * 16));
    #pragma unroll
    for (int nf = 0; nf < 4; nf++)
      bfv[nf] = *(const bf16x8*)((const char*)bs + bpr_off(wn * 64 + nf * 16 + l15, lq * 16));
    #pragma unroll
    for (int mf = 0; mf < 4; mf++)
      #pragma unroll
      for (int nf = 0; nf < 4; nf++)
        acc[mf][nf] = MFMA16(af[mf], bfv[nf], acc[mf][nf]);
  }

  #pragma unroll
  for (int mf = 0; mf < 4; mf++)
    #pragma unroll
    for (int nf = 0; nf < 4; nf++)
      #pragma unroll
      for (int r = 0; r < 4; r++) {
        const int gr = row0 + wm * 64 + mf * 16 + lq * 4 + r;
        const int gc = col0 + wn * 64 + nf * 16 + l15;
        outf[(size_t)gr * 1024 + gc] = acc[mf][nf][r] + bias[gc];
      }
}

// ---------------- causal flash attention (round-5 EXACT, known-pass) ----------------
__global__ __launch_bounds__(256) void attn_kernel(const short* __restrict__ Qh,
                                                   const short* __restrict__ Kh,
                                                   const short* __restrict__ Vtr,
                                                   short* __restrict__ attnout) {
  __shared__ __align__(16) short Ks[2][64 * 64];   // [kv][hd] swizzled
  __shared__ __align__(16) short Vs[2][64 * 64];   // [hd][kv] swizzled
  __shared__ __align__(16) short Ps[4][32 * 64];   // per-wave P[q][kv] swizzled
  const int tid = threadIdx.x, l = tid & 63, w = tid >> 6;
  const int l15 = l & 15, lq = l >> 4;
  const int flat = blockIdx.x;
  const int vid = (flat & 7) * 64 + (flat >> 3);   // 8 bh per XCD (K+V working set ~4MB = L2)
  const int bh = vid >> 3, pairx = vid & 7;
  const int b = bh >> 4, h = bh & 15;
  const size_t base = (size_t)bh * (S_ * HD_);
  const short* Qp = Qh + base;
  const short* Kp = Kh + base;
  const short* Vp = Vtr + base;   // [64][2048]
  short* Pw = (short*)Ps[w];

  for (int pass = 0; pass < 2; ++pass) {
    const int qt = pass ? 15 - pairx : pairx;      // diagonal pairing: total work uniform
    const int q0 = qt * 128;
    const int qw = q0 + w * 32;
    const int nkt = (q0 >> 6) + 2;

    // Q B-fragments (q already pre-scaled by 0.125*log2e in the Q projection)
    bf16x8 qf[2][2];
    #pragma unroll
    for (int qh = 0; qh < 2; qh++)
      #pragma unroll
      for (int ks = 0; ks < 2; ks++)
        qf[qh][ks] = *(const bf16x8*)(Qp + (size_t)(qw + qh * 16 + l15) * 64 + ks * 32 + lq * 8);

    f32x4 oacc[4][2] = {};          // [hd-frag][q-half]: O^T, rows hd, cols q=l15
    float mrow[2] = {-1e30f, -1e30f};
    float lpart[2] = {0.f, 0.f};    // per-lane partial row-sum (reduced only at epilogue)

    auto stage = [&](int kt, int bf) {
      const int k0s = kt << 6;
      #pragma unroll
      for (int i = 0; i < 2; i++) {
        const int o = w * 2048 + i * 1024 + l * 16;          // byte offset in 8KB tile
        const int sw = o ^ (((o >> 7) & 7) << 4);            // inverse-swizzled source (rule 21)
        gload_lds16((const char*)Kp + (size_t)k0s * 128 + sw, (char*)Ks[bf] + o);
        gload_lds16(Vp + (size_t)(o >> 7) * S_ + k0s + ((sw & 127) >> 1), (char*)Vs[bf] + o);
      }
    };

    stage(0, 0);
    __syncthreads();

    for (int kt = 0; kt < nkt; ++kt) {
      const int cur = kt & 1;
      if (kt + 1 < nkt) stage(kt + 1, cur ^ 1);   // prefetch in flight across compute
      const int k0 = kt << 6;

      if (k0 <= qw + 31) {                         // wave-level fully-masked-tile skip
        // --- QK^T swapped: sacc[qh][mf] holds S^T[kv=16mf+4lq+r][q=16qh+l15] ---
        f32x4 sacc[2][4] = {};
        __builtin_amdgcn_s_setprio(1);
        #pragma unroll
        for (int ks = 0; ks < 2; ks++) {
          #pragma unroll
          for (int mf = 0; mf < 4; mf++) {
            const bf16x8 kf = ldsw8(Ks[cur], mf * 16 + l15, ks * 64 + lq * 16);
            #pragma unroll
            for (int qh = 0; qh < 2; qh++)
              sacc[qh][mf] = MFMA16(kf, qf[qh][ks], sacc[qh][mf]);
          }
        }
        __builtin_amdgcn_s_setprio(0);

        // causal mask — only diagonal tiles
        if (k0 + 63 > qw) {
          #pragma unroll
          for (int qh = 0; qh < 2; qh++) {
            const int qg = qw + qh * 16 + l15 - lq * 4;   // kv>q  <=>  k0+16mf+r > qg
            #pragma unroll
            for (int mf = 0; mf < 4; mf++)
              #pragma unroll
              for (int r = 0; r < 4; r++)
                if (k0 + mf * 16 + r > qg) sacc[qh][mf][r] = -1e30f;
          }
        }

        // per-lane local max (no shfl unless rescale fires)
        float mxl[2];
        #pragma unroll
        for (int qh = 0; qh < 2; qh++) {
          float m = fmaxf(fmaxf(sacc[qh][0][0], sacc[qh][0][1]),
                          fmaxf(sacc[qh][0][2], sacc[qh][0][3]));
          #pragma unroll
          for (int mf = 1; mf < 4; mf++)
            m = fmaxf(m, fmaxf(fmaxf(sacc[qh][mf][0], sacc[qh][mf][1]),
                               fmaxf(sacc[qh][mf][2], sacc[qh][mf][3])));
          mxl[qh] = m;
        }

        // defer-max (T13, THR=8 in log2 domain); lane-max trigger == row-max trigger
        const bool need = (mxl[0] > mrow[0] + 8.f) || (mxl[1] > mrow[1] + 8.f);
        if (__any(need)) {
          #pragma unroll
          for (int qh = 0; qh < 2; qh++) {
            float m = fmaxf(mxl[qh], __shfl_xor(mxl[qh], 16));
            m = fmaxf(m, __shfl_xor(m, 32));
            const float mn = fmaxf(mrow[qh], m);
            const float fac = __builtin_amdgcn_exp2f(mrow[qh] - mn);
            mrow[qh] = mn;
            lpart[qh] *= fac;
            #pragma unroll
            for (int mf = 0; mf < 4; mf++) oacc[mf][qh] *= fac;
          }
        }

        // exp2, per-lane sum, HW-packed P -> per-wave LDS (8 x ds_write_b64)
        #pragma unroll
        for (int qh = 0; qh < 2; qh++) {
          float rs = 0.f;
          const int row = qh * 16 + l15;
          #pragma unroll
          for (int mf = 0; mf < 4; mf++) {
            f32x4 p;
            #pragma unroll
            for (int r = 0; r < 4; r++) {
              const float e = __builtin_amdgcn_exp2f(sacc[qh][mf][r] - mrow[qh]);
              p[r] = e;
              rs += e;
            }
            const int off = (row * 128 + mf * 32 + lq * 8) ^ ((row & 7) << 4);
            *(uint2*)((char*)Pw + off) = make_uint2(cvtpk(p[0], p[1]), cvtpk(p[2], p[3]));
          }
          lpart[qh] += rs;
        }

        asm volatile("s_waitcnt lgkmcnt(0)" ::: "memory");
        __builtin_amdgcn_sched_barrier(0);

        // --- PV swapped: oacc[mf][qh] += V^T-frag x P^T-frag ---
        __builtin_amdgcn_s_setprio(1);
        #pragma unroll
        for (int ks = 0; ks < 2; ks++) {
          bf16x8 pb[2];
          #pragma unroll
          for (int qh = 0; qh < 2; qh++) {
            const int row = qh * 16 + l15;
            const int off = (row * 128 + ks * 64 + lq * 16) ^ ((row & 7) << 4);
            pb[qh] = *(const bf16x8*)((const char*)Pw + off);
          }
          #pragma unroll
          for (int mf = 0; mf < 4; mf++) {
            const bf16x8 vf = ldsw8(Vs[cur], mf * 16 + l15, ks * 64 + lq * 16);
            #pragma unroll
            for (int qh = 0; qh < 2; qh++)
              oacc[mf][qh] = MFMA16(vf, pb[qh], oacc[mf][qh]);
          }
        }
        __builtin_amdgcn_s_setprio(0);
      }
      __syncthreads();   // prefetch drained (vmcnt) + all waves done with buf cur
    }

    // epilogue: O^T rows hd=16mf+4lq+r, col q=16qh+l15 -> attnout [B][S][H*HD]
    #pragma unroll
    for (int qh = 0; qh < 2; qh++) {
      float lr = lpart[qh];
      lr += __shfl_xor(lr, 16);
      lr += __shfl_xor(lr, 32);
      const float rinv = __builtin_amdgcn_rcpf(lr);
      const int q = qw + qh * 16 + l15;
      #pragma unroll
      for (int mf = 0; mf < 4; mf++) {
        const f32x4 o = oacc[mf][qh];
        const uint2 u = make_uint2(cvtpk(o[0] * rinv, o[1] * rinv),
                                   cvtpk(o[2] * rinv, o[3] * rinv));
        *(uint2*)(attnout + ((size_t)b * S_ + q) * (H_ * HD_) + h * 64 + mf * 16 + lq * 4) = u;
      }
    }
  }
}

extern "C" void kernel_launch(void* const* d_in, const int* in_sizes, int n_in,
                              void* d_out, int out_size, void* d_ws, size_t ws_size,
                              hipStream_t stream) {
  const float* query = (const float*)d_in[0];
  const float* key_  = (const float*)d_in[1];
  const float* value = (const float*)d_in[2];
  // d_in[3] = causal mask — implied analytically
  const float* Wq = (const float*)d_in[4];
  const float* Wk = (const float*)d_in[5];
  const float* Wv = (const float*)d_in[6];
  const float* Wo = (const float*)d_in[7];
  const float* bo = (const float*)d_in[8];
  float* out = (float*)d_out;

  char* ws = (char*)d_ws;
  const size_t MB = (size_t)1 << 20;
  short* Xbuf = (short*)(ws);             // 16 MB: attn output
  short* Wqt  = (short*)(ws + 16 * MB);
  short* Wkt  = (short*)(ws + 18 * MB);
  short* Wvt  = (short*)(ws + 20 * MB);
  short* Wot  = (short*)(ws + 22 * MB);
  short* Qh   = (short*)(ws + 24 * MB);   // 16 MB [B][H][S][HD], pre-scaled by 0.125*log2e
  short* Kh   = (short*)(ws + 40 * MB);   // 16 MB [B][H][S][HD]
  short* Vt   = (short*)(ws + 56 * MB);   // 16 MB [B][H][HD][S]   (total 72 MB)

  const dim3 tb(32, 8);
  const dim3 tg4(32, 32, 4);
  const float QSCALE = 0.125f * 1.4426950408889634f;  // fold 1/sqrt(HD) * log2(e) into Q

  transpose_cast_w4<<<tg4, tb, 0, stream>>>(Wq, Wk, Wv, Wo, Wqt, Wkt, Wvt, Wot);

  gemm8<<<dim3(4, 32, 3), 512, 0, stream>>>(query, key_, value, Wqt, Wkt, Wvt,
                                            Qh, Kh, Vt, QSCALE);

  attn_kernel<<<dim3(512), 256, 0, stream>>>(Qh, Kh, Vt, Xbuf);

  gemm_o<<<dim3(8, 64), 256, 0, stream>>>(Xbuf, Wot, out, bo);
}

// Round 10
// 226.677 us; speedup vs baseline: 1.0736x; 1.0736x over previous
//
#include <hip/hip_runtime.h>

#define B_ 4
#define S_ 2048
#define D_ 1024
#define H_ 16
#define HD_ 64

typedef __attribute__((ext_vector_type(8))) short bf16x8;
typedef __attribute__((ext_vector_type(4))) float f32x4;
typedef __attribute__((ext_vector_type(4))) unsigned u32x4;

__device__ __forceinline__ short f2bf(float f) {
  unsigned u = __builtin_bit_cast(unsigned, f);
  u += 0x7fffu + ((u >> 16) & 1u);   // RNE
  return (short)(u >> 16);
}

// HW packed f32x2 -> bf16x2 (RNE); no builtin on gfx950 -> inline asm (T12)
__device__ __forceinline__ unsigned cvtpk(float a, float b) {
  unsigned r;
  asm("v_cvt_pk_bf16_f32 %0, %1, %2" : "=v"(r) : "v"(a), "v"(b));
  return r;
}

__device__ __forceinline__ void gload_lds16(const void* g, void* l) {
  __builtin_amdgcn_global_load_lds((const __attribute__((address_space(1))) void*)g,
                                   (__attribute__((address_space(3))) void*)l, 16, 0, 0);
}

// swizzled LDS bf16x8 read from a [rows][64] bf16 tile (128B rows, T2 XOR swizzle)
__device__ __forceinline__ bf16x8 ldsw8(const short* base, int row, int colb) {
  const int off = (row * 128 + colb) ^ ((row & 7) << 4);
  return *(const bf16x8*)((const char*)base + off);
}

// pair-row swizzle for 64B-row bf16 tiles ([rows][32 shorts])
__device__ __forceinline__ int bpr_off(int row, int cbyte) {
  return ((row >> 1) << 7) + ((((row & 1) << 6) + cbyte) ^ (((row >> 1) & 7) << 4));
}

#define MFMA16(a, b, c) __builtin_amdgcn_mfma_f32_16x16x32_bf16((a), (b), (c), 0, 0, 0)
#define PBAR()   asm volatile("s_barrier" ::: "memory")
#define LGKM0()  do { asm volatile("s_waitcnt lgkmcnt(0)" ::: "memory"); \
                      __builtin_amdgcn_sched_barrier(0); } while (0)

// ---------------- 4x W [K][N] f32 -> Wt [N][K] bf16, one dispatch ----------------
__global__ void transpose_cast_w4(const float* __restrict__ W0, const float* __restrict__ W1,
                                  const float* __restrict__ W2, const float* __restrict__ W3,
                                  short* __restrict__ T0, short* __restrict__ T1,
                                  short* __restrict__ T2, short* __restrict__ T3) {
  __shared__ float tile[32][33];
  const int z = blockIdx.z;
  const float* W = z == 0 ? W0 : z == 1 ? W1 : z == 2 ? W2 : W3;
  short* Wt = z == 0 ? T0 : z == 1 ? T1 : z == 2 ? T2 : T3;
  const int n0 = blockIdx.x * 32, k0 = blockIdx.y * 32;
  const int tx = threadIdx.x, ty = threadIdx.y;  // 32 x 8
  #pragma unroll
  for (int i = ty; i < 32; i += 8)
    tile[i][tx] = W[(size_t)(k0 + i) * 1024 + n0 + tx];
  __syncthreads();
  #pragma unroll
  for (int i = ty; i < 32; i += 8)
    Wt[(size_t)(n0 + i) * 1024 + k0 + tx] = f2bf(tile[tx][i]);
}

// ---- fused-cast QKV GEMM: 256x128x64 tiles, 2-phase/tile, counted vmcnt (R7 invariant) ----
// 512 thr = 8 waves (4M x 2N); wave = 64x64 out (acc[4][4]).  LDS = 160KB:
//   AsF[2] f32 64KB (256 rows x 256B, XOR-swz src) ; Bs[2] bf16 16KB (128 rows x 128B, XOR-swz).
// Schedule per tile t: entry {vmcnt(2|0); s_barrier};
//   ph0: issue A(t+1)[0..3] -> AsF[o]; read B-frags+A-frags(mf0,1); lgkm0; 16 MFMA; s_barrier
//   ph1: issue A(t+1)[4..7] -> AsF[o]; issue B(t+2) -> Bs[c] (LAST); read A-frags(mf2,3);
//        lgkm0; 16 MFMA   (next entry barrier closes the tile)
// Entry wait derivation: program order ... B(t), A(t)x8, B(t+1) -> vmcnt(2) completes A(t)+B(t).
// z==0: Q out [B][H][S][HD]*qscale; z==1: K out; z==2: V out [B][H][HD][S].
__global__ __launch_bounds__(512, 1) void gemm_qkv8(const float* __restrict__ Aq,
                                                    const float* __restrict__ Ak,
                                                    const float* __restrict__ Av,
                                                    const short* __restrict__ Bq,
                                                    const short* __restrict__ Bk,
                                                    const short* __restrict__ Bv,
                                                    short* __restrict__ Oq,
                                                    short* __restrict__ Ok,
                                                    short* __restrict__ Ov,
                                                    float qscale) {
  __shared__ __align__(16) float AsF[2][16384];   // 2 x 64KB
  __shared__ __align__(16) short Bs[2][8192];     // 2 x 16KB
  const int z = blockIdx.z;
  const float* A = z == 0 ? Aq : z == 1 ? Ak : Av;
  const short* Bt = z == 0 ? Bq : z == 1 ? Bk : Bv;
  short* outb = z == 0 ? Oq : z == 1 ? Ok : Ov;
  const float oscale = (z == 0) ? qscale : 1.0f;

  const int tid = threadIdx.x;
  const int l = tid & 63, w = tid >> 6;
  const int wm = w >> 1, wn = w & 1;               // 4M x 2N waves, wave = 64x64
  const int l15 = l & 15, lq = l >> 4;
  const int flat8 = blockIdx.x + (blockIdx.y << 3);  // grid (8, 32, 3) -> 256 per z
  const int vid = (flat8 & 7) * 32 + (flat8 >> 3);   // XCD-grouped remap
  const int row0 = (vid >> 3) * 256;                 // 32 row-tiles
  const int col0 = (vid & 7) * 128;                  // 8 col-tiles

  f32x4 acc[4][4] = {};

  // A f32 tile 256x64 (256B rows); batch = 4 of 8 issues (64KB / 512thr / 16B = 8)
  auto stageA = [&](int kt, int buf, int batch) {
    #pragma unroll
    for (int j = 0; j < 4; ++j) {
      const int o2 = w * 8192 + (batch * 4 + j) * 1024 + l * 16;
      const int row = o2 >> 8;
      const int sc = (o2 & 255) ^ ((row & 7) << 4);
      gload_lds16((const char*)A + (size_t)(row0 + row) * 4096 + kt * 256 + sc,
                  (char*)AsF[buf] + o2);
    }
  };
  // B bf16 tile 128x64 (128B rows); 2 issues
  auto stageB = [&](int kt) {
    const int buf = kt & 1;
    #pragma unroll
    for (int j = 0; j < 2; ++j) {
      const int o2 = w * 2048 + j * 1024 + l * 16;
      const int row = o2 >> 7;
      const int sc = (o2 & 127) ^ ((row & 7) << 4);
      gload_lds16((const char*)Bt + (size_t)(col0 + row) * 2048 + kt * 128 + sc,
                  (char*)Bs[buf] + o2);
    }
  };
  // f32 A-fragment read + packed convert (256B rows, same XOR swizzle)
  auto rdA = [&](const float* as, int R, int ks) -> bf16x8 {
    const int c0 = (ks * 128 + lq * 32) ^ ((R & 7) << 4);
    const f32x4 g0 = *(const f32x4*)((const char*)as + R * 256 + c0);
    const f32x4 g1 = *(const f32x4*)((const char*)as + R * 256 + (c0 ^ 16));
    const u32x4 uu = {cvtpk(g0[0], g0[1]), cvtpk(g0[2], g0[3]),
                      cvtpk(g1[0], g1[1]), cvtpk(g1[2], g1[3])};
    return __builtin_bit_cast(bf16x8, uu);
  };

  // prologue (program order: A(0) x8, B(0), B(1))
  stageA(0, 0, 0);
  stageA(0, 0, 1);
  stageB(0);
  stageB(1);

  for (int t = 0; t < 16; ++t) {
    const int c = t & 1, o = c ^ 1;
    if (t < 15) asm volatile("s_waitcnt vmcnt(2)" ::: "memory");
    else        asm volatile("s_waitcnt vmcnt(0)" ::: "memory");
    PBAR();

    const float* Ah = AsF[c];
    const short* Bh = Bs[c];
    bf16x8 bfr[4][2];

    // ---- phase 0: mf 0,1 ----
    if (t + 1 < 16) stageA(t + 1, o, 0);
    #pragma unroll
    for (int nf = 0; nf < 4; ++nf)
      #pragma unroll
      for (int ks = 0; ks < 2; ++ks)
        bfr[nf][ks] = ldsw8(Bh, wn * 64 + nf * 16 + l15, ks * 64 + lq * 16);
    {
      const bf16x8 a00 = rdA(Ah, wm * 64 + 0 * 16 + l15, 0);
      const bf16x8 a01 = rdA(Ah, wm * 64 + 0 * 16 + l15, 1);
      const bf16x8 a10 = rdA(Ah, wm * 64 + 1 * 16 + l15, 0);
      const bf16x8 a11 = rdA(Ah, wm * 64 + 1 * 16 + l15, 1);
      LGKM0();
      __builtin_amdgcn_s_setprio(1);
      #pragma unroll
      for (int nf = 0; nf < 4; ++nf) {
        acc[0][nf] = MFMA16(a00, bfr[nf][0], acc[0][nf]);
        acc[0][nf] = MFMA16(a01, bfr[nf][1], acc[0][nf]);
        acc[1][nf] = MFMA16(a10, bfr[nf][0], acc[1][nf]);
        acc[1][nf] = MFMA16(a11, bfr[nf][1], acc[1][nf]);
      }
      __builtin_amdgcn_s_setprio(0);
    }
    PBAR();

    // ---- phase 1: mf 2,3 ----
    if (t + 1 < 16) stageA(t + 1, o, 1);
    if (t + 2 < 16) stageB(t + 2);          // issued LAST -> counted entry wait
    {
      const bf16x8 a00 = rdA(Ah, wm * 64 + 2 * 16 + l15, 0);
      const bf16x8 a01 = rdA(Ah, wm * 64 + 2 * 16 + l15, 1);
      const bf16x8 a10 = rdA(Ah, wm * 64 + 3 * 16 + l15, 0);
      const bf16x8 a11 = rdA(Ah, wm * 64 + 3 * 16 + l15, 1);
      LGKM0();
      __builtin_amdgcn_s_setprio(1);
      #pragma unroll
      for (int nf = 0; nf < 4; ++nf) {
        acc[2][nf] = MFMA16(a00, bfr[nf][0], acc[2][nf]);
        acc[2][nf] = MFMA16(a01, bfr[nf][1], acc[2][nf]);
        acc[3][nf] = MFMA16(a10, bfr[nf][0], acc[3][nf]);
        acc[3][nf] = MFMA16(a11, bfr[nf][1], acc[3][nf]);
      }
      __builtin_amdgcn_s_setprio(0);
    }
    // next tile's entry barrier closes this tile
  }

  // epilogue: C/D layout col=lane&15, row=(lane>>4)*4+reg
  #pragma unroll
  for (int mf = 0; mf < 4; ++mf) {
    #pragma unroll
    for (int nf = 0; nf < 4; ++nf) {
      #pragma unroll
      for (int r = 0; r < 4; ++r) {
        const int gr = row0 + wm * 64 + mf * 16 + lq * 4 + r;  // m = b*S + s
        const int gc = col0 + wn * 64 + nf * 16 + l15;         // n = h*64 + hd
        const float v = acc[mf][nf][r];
        const int b = gr >> 11, s = gr & 2047;
        const int h = gc >> 6, hd = gc & 63;
        if (z < 2)
          outb[(((size_t)(b * H_ + h)) * S_ + s) * HD_ + hd] = f2bf(v * oscale);
        else
          outb[(((size_t)(b * H_ + h)) * HD_ + hd) * S_ + s] = f2bf(v);
      }
    }
  }
}

// ---------------- O-projection GEMM (proven): f32 out = A_bf16 @ Wot^T + bias ----------------
__global__ __launch_bounds__(256) void gemm_o(const short* __restrict__ A,
                                              const short* __restrict__ Bt,
                                              float* __restrict__ outf,
                                              const float* __restrict__ bias) {
  __shared__ __align__(16) short As[2][128 * 32];
  __shared__ __align__(16) short Bs[2][128 * 32];
  const int tid = threadIdx.x;
  const int l = tid & 63;
  const int w = tid >> 6;
  const int wm = w >> 1, wn = w & 1;
  const int flat = blockIdx.x + (blockIdx.y << 3);
  const int xcd = flat & 7, t = flat >> 3;
  const int row0 = (xcd * 8 + (t & 7)) * 128;
  const int col0 = (t >> 3) * 128;
  const int l15 = l & 15, lq = l >> 4;

  f32x4 acc[4][4] = {};

  auto stage = [&](const short* src, int r0, int k0, short* lds) {
    #pragma unroll
    for (int i = 0; i < 2; i++) {
      const int o = w * 2048 + i * 1024 + l * 16;
      const int row2 = o >> 7;
      const int ip = (o & 127) ^ ((row2 & 7) << 4);
      const int row = row2 * 2 + (ip >> 6);
      const int cb = ip & 63;
      gload_lds16((const char*)src + ((size_t)(r0 + row) * 1024 + k0) * 2 + cb,
                  (char*)lds + o);
    }
  };

  stage(A, row0, 0, As[0]);
  stage(Bt, col0, 0, Bs[0]);

  for (int kt = 0; kt < 32; ++kt) {
    __syncthreads();
    if (kt + 1 < 32) {
      stage(A, row0, (kt + 1) * 32, As[(kt + 1) & 1]);
      stage(Bt, col0, (kt + 1) * 32, Bs[(kt + 1) & 1]);
    }
    const short* as = As[kt & 1];
    const short* bs = Bs[kt & 1];
    bf16x8 af[4], bfv[4];
    #pragma unroll
    for (int mf = 0; mf < 4; mf++)
      af[mf] = *(const bf16x8*)((const char*)as + bpr_off(wm * 64 + mf * 16 + l15, lq * 16));
    #pragma unroll
    for (int nf = 0; nf < 4; nf++)
      bfv[nf] = *(const bf16x8*)((const char*)bs + bpr_off(wn * 64 + nf * 16 + l15, lq * 16));
    #pragma unroll
    for (int mf = 0; mf < 4; mf++)
      #pragma unroll
      for (int nf = 0; nf < 4; nf++)
        acc[mf][nf] = MFMA16(af[mf], bfv[nf], acc[mf][nf]);
  }

  #pragma unroll
  for (int mf = 0; mf < 4; mf++)
    #pragma unroll
    for (int nf = 0; nf < 4; nf++)
      #pragma unroll
      for (int r = 0; r < 4; r++) {
        const int gr = row0 + wm * 64 + mf * 16 + lq * 4 + r;
        const int gc = col0 + wn * 64 + nf * 16 + l15;
        outf[(size_t)gr * 1024 + gc] = acc[mf][nf][r] + bias[gc];
      }
}

// ---------------- causal flash attention (round-5 EXACT, known-pass) ----------------
__global__ __launch_bounds__(256) void attn_kernel(const short* __restrict__ Qh,
                                                   const short* __restrict__ Kh,
                                                   const short* __restrict__ Vtr,
                                                   short* __restrict__ attnout) {
  __shared__ __align__(16) short Ks[2][64 * 64];   // [kv][hd] swizzled
  __shared__ __align__(16) short Vs[2][64 * 64];   // [hd][kv] swizzled
  __shared__ __align__(16) short Ps[4][32 * 64];   // per-wave P[q][kv] swizzled
  const int tid = threadIdx.x, l = tid & 63, w = tid >> 6;
  const int l15 = l & 15, lq = l >> 4;
  const int flat = blockIdx.x;
  const int vid = (flat & 7) * 64 + (flat >> 3);   // 8 bh per XCD (K+V working set ~4MB = L2)
  const int bh = vid >> 3, pairx = vid & 7;
  const int b = bh >> 4, h = bh & 15;
  const size_t base = (size_t)bh * (S_ * HD_);
  const short* Qp = Qh + base;
  const short* Kp = Kh + base;
  const short* Vp = Vtr + base;   // [64][2048]
  short* Pw = (short*)Ps[w];

  for (int pass = 0; pass < 2; ++pass) {
    const int qt = pass ? 15 - pairx : pairx;      // diagonal pairing: total work uniform
    const int q0 = qt * 128;
    const int qw = q0 + w * 32;
    const int nkt = (q0 >> 6) + 2;

    // Q B-fragments (q already pre-scaled by 0.125*log2e in the Q projection)
    bf16x8 qf[2][2];
    #pragma unroll
    for (int qh = 0; qh < 2; qh++)
      #pragma unroll
      for (int ks = 0; ks < 2; ks++)
        qf[qh][ks] = *(const bf16x8*)(Qp + (size_t)(qw + qh * 16 + l15) * 64 + ks * 32 + lq * 8);

    f32x4 oacc[4][2] = {};          // [hd-frag][q-half]: O^T, rows hd, cols q=l15
    float mrow[2] = {-1e30f, -1e30f};
    float lpart[2] = {0.f, 0.f};    // per-lane partial row-sum (reduced only at epilogue)

    auto stage = [&](int kt, int bf) {
      const int k0s = kt << 6;
      #pragma unroll
      for (int i = 0; i < 2; i++) {
        const int o = w * 2048 + i * 1024 + l * 16;          // byte offset in 8KB tile
        const int sw = o ^ (((o >> 7) & 7) << 4);            // inverse-swizzled source (rule 21)
        gload_lds16((const char*)Kp + (size_t)k0s * 128 + sw, (char*)Ks[bf] + o);
        gload_lds16(Vp + (size_t)(o >> 7) * S_ + k0s + ((sw & 127) >> 1), (char*)Vs[bf] + o);
      }
    };

    stage(0, 0);
    __syncthreads();

    for (int kt = 0; kt < nkt; ++kt) {
      const int cur = kt & 1;
      if (kt + 1 < nkt) stage(kt + 1, cur ^ 1);   // prefetch in flight across compute
      const int k0 = kt << 6;

      if (k0 <= qw + 31) {                         // wave-level fully-masked-tile skip
        // --- QK^T swapped: sacc[qh][mf] holds S^T[kv=16mf+4lq+r][q=16qh+l15] ---
        f32x4 sacc[2][4] = {};
        __builtin_amdgcn_s_setprio(1);
        #pragma unroll
        for (int ks = 0; ks < 2; ks++) {
          #pragma unroll
          for (int mf = 0; mf < 4; mf++) {
            const bf16x8 kf = ldsw8(Ks[cur], mf * 16 + l15, ks * 64 + lq * 16);
            #pragma unroll
            for (int qh = 0; qh < 2; qh++)
              sacc[qh][mf] = MFMA16(kf, qf[qh][ks], sacc[qh][mf]);
          }
        }
        __builtin_amdgcn_s_setprio(0);

        // causal mask — only diagonal tiles
        if (k0 + 63 > qw) {
          #pragma unroll
          for (int qh = 0; qh < 2; qh++) {
            const int qg = qw + qh * 16 + l15 - lq * 4;   // kv>q  <=>  k0+16mf+r > qg
            #pragma unroll
            for (int mf = 0; mf < 4; mf++)
              #pragma unroll
              for (int r = 0; r < 4; r++)
                if (k0 + mf * 16 + r > qg) sacc[qh][mf][r] = -1e30f;
          }
        }

        // per-lane local max (no shfl unless rescale fires)
        float mxl[2];
        #pragma unroll
        for (int qh = 0; qh < 2; qh++) {
          float m = fmaxf(fmaxf(sacc[qh][0][0], sacc[qh][0][1]),
                          fmaxf(sacc[qh][0][2], sacc[qh][0][3]));
          #pragma unroll
          for (int mf = 1; mf < 4; mf++)
            m = fmaxf(m, fmaxf(fmaxf(sacc[qh][mf][0], sacc[qh][mf][1]),
                               fmaxf(sacc[qh][mf][2], sacc[qh][mf][3])));
          mxl[qh] = m;
        }

        // defer-max (T13, THR=8 in log2 domain); lane-max trigger == row-max trigger
        const bool need = (mxl[0] > mrow[0] + 8.f) || (mxl[1] > mrow[1] + 8.f);
        if (__any(need)) {
          #pragma unroll
          for (int qh = 0; qh < 2; qh++) {
            float m = fmaxf(mxl[qh], __shfl_xor(mxl[qh], 16));
            m = fmaxf(m, __shfl_xor(m, 32));
            const float mn = fmaxf(mrow[qh], m);
            const float fac = __builtin_amdgcn_exp2f(mrow[qh] - mn);
            mrow[qh] = mn;
            lpart[qh] *= fac;
            #pragma unroll
            for (int mf = 0; mf < 4; mf++) oacc[mf][qh] *= fac;
          }
        }

        // exp2, per-lane sum, HW-packed P -> per-wave LDS (8 x ds_write_b64)
        #pragma unroll
        for (int qh = 0; qh < 2; qh++) {
          float rs = 0.f;
          const int row = qh * 16 + l15;
          #pragma unroll
          for (int mf = 0; mf < 4; mf++) {
            f32x4 p;
            #pragma unroll
            for (int r = 0; r < 4; r++) {
              const float e = __builtin_amdgcn_exp2f(sacc[qh][mf][r] - mrow[qh]);
              p[r] = e;
              rs += e;
            }
            const int off = (row * 128 + mf * 32 + lq * 8) ^ ((row & 7) << 4);
            *(uint2*)((char*)Pw + off) = make_uint2(cvtpk(p[0], p[1]), cvtpk(p[2], p[3]));
          }
          lpart[qh] += rs;
        }

        asm volatile("s_waitcnt lgkmcnt(0)" ::: "memory");
        __builtin_amdgcn_sched_barrier(0);

        // --- PV swapped: oacc[mf][qh] += V^T-frag x P^T-frag ---
        __builtin_amdgcn_s_setprio(1);
        #pragma unroll
        for (int ks = 0; ks < 2; ks++) {
          bf16x8 pb[2];
          #pragma unroll
          for (int qh = 0; qh < 2; qh++) {
            const int row = qh * 16 + l15;
            const int off = (row * 128 + ks * 64 + lq * 16) ^ ((row & 7) << 4);
            pb[qh] = *(const bf16x8*)((const char*)Pw + off);
          }
          #pragma unroll
          for (int mf = 0; mf < 4; mf++) {
            const bf16x8 vf = ldsw8(Vs[cur], mf * 16 + l15, ks * 64 + lq * 16);
            #pragma unroll
            for (int qh = 0; qh < 2; qh++)
              oacc[mf][qh] = MFMA16(vf, pb[qh], oacc[mf][qh]);
          }
        }
        __builtin_amdgcn_s_setprio(0);
      }
      __syncthreads();   // prefetch drained (vmcnt) + all waves done with buf cur
    }

    // epilogue: O^T rows hd=16mf+4lq+r, col q=16qh+l15 -> attnout [B][S][H*HD]
    #pragma unroll
    for (int qh = 0; qh < 2; qh++) {
      float lr = lpart[qh];
      lr += __shfl_xor(lr, 16);
      lr += __shfl_xor(lr, 32);
      const float rinv = __builtin_amdgcn_rcpf(lr);
      const int q = qw + qh * 16 + l15;
      #pragma unroll
      for (int mf = 0; mf < 4; mf++) {
        const f32x4 o = oacc[mf][qh];
        const uint2 u = make_uint2(cvtpk(o[0] * rinv, o[1] * rinv),
                                   cvtpk(o[2] * rinv, o[3] * rinv));
        *(uint2*)(attnout + ((size_t)b * S_ + q) * (H_ * HD_) + h * 64 + mf * 16 + lq * 4) = u;
      }
    }
  }
}

extern "C" void kernel_launch(void* const* d_in, const int* in_sizes, int n_in,
                              void* d_out, int out_size, void* d_ws, size_t ws_size,
                              hipStream_t stream) {
  const float* query = (const float*)d_in[0];
  const float* key_  = (const float*)d_in[1];
  const float* value = (const float*)d_in[2];
  // d_in[3] = causal mask — implied analytically
  const float* Wq = (const float*)d_in[4];
  const float* Wk = (const float*)d_in[5];
  const float* Wv = (const float*)d_in[6];
  const float* Wo = (const float*)d_in[7];
  const float* bo = (const float*)d_in[8];
  float* out = (float*)d_out;

  char* ws = (char*)d_ws;
  const size_t MB = (size_t)1 << 20;
  short* Xbuf = (short*)(ws);             // 16 MB: attn output
  short* Wqt  = (short*)(ws + 16 * MB);
  short* Wkt  = (short*)(ws + 18 * MB);
  short* Wvt  = (short*)(ws + 20 * MB);
  short* Wot  = (short*)(ws + 22 * MB);
  short* Qh   = (short*)(ws + 24 * MB);   // 16 MB [B][H][S][HD], pre-scaled by 0.125*log2e
  short* Kh   = (short*)(ws + 40 * MB);   // 16 MB [B][H][S][HD]
  short* Vt   = (short*)(ws + 56 * MB);   // 16 MB [B][H][HD][S]   (total 72 MB)

  const dim3 tb(32, 8);
  const dim3 tg4(32, 32, 4);
  const float QSCALE = 0.125f * 1.4426950408889634f;  // fold 1/sqrt(HD) * log2(e) into Q

  transpose_cast_w4<<<tg4, tb, 0, stream>>>(Wq, Wk, Wv, Wo, Wqt, Wkt, Wvt, Wot);

  gemm_qkv8<<<dim3(8, 32, 3), 512, 0, stream>>>(query, key_, value, Wqt, Wkt, Wvt,
                                                Qh, Kh, Vt, QSCALE);

  attn_kernel<<<dim3(512), 256, 0, stream>>>(Qh, Kh, Vt, Xbuf);

  gemm_o<<<dim3(8, 64), 256, 0, stream>>>(Xbuf, Wot, out, bo);
}

// Round 12
// 199.175 us; speedup vs baseline: 1.2218x; 1.1381x over previous
//
#include <hip/hip_runtime.h>

#define B_ 4
#define S_ 2048
#define D_ 1024
#define H_ 16
#define HD_ 64

typedef __attribute__((ext_vector_type(8))) short bf16x8;
typedef __attribute__((ext_vector_type(4))) float f32x4;
typedef __attribute__((ext_vector_type(4))) unsigned u32x4;

__device__ __forceinline__ short f2bf(float f) {
  unsigned u = __builtin_bit_cast(unsigned, f);
  u += 0x7fffu + ((u >> 16) & 1u);   // RNE
  return (short)(u >> 16);
}

// HW packed f32x2 -> bf16x2 (RNE); no builtin on gfx950 -> inline asm (T12)
__device__ __forceinline__ unsigned cvtpk(float a, float b) {
  unsigned r;
  asm("v_cvt_pk_bf16_f32 %0, %1, %2" : "=v"(r) : "v"(a), "v"(b));
  return r;
}

__device__ __forceinline__ void gload_lds16(const void* g, void* l) {
  __builtin_amdgcn_global_load_lds((const __attribute__((address_space(1))) void*)g,
                                   (__attribute__((address_space(3))) void*)l, 16, 0, 0);
}

// swizzled LDS bf16x8 read from a [rows][64] bf16 tile (128B rows, T2 XOR swizzle)
__device__ __forceinline__ bf16x8 ldsw8(const short* base, int row, int colb) {
  const int off = (row * 128 + colb) ^ ((row & 7) << 4);
  return *(const bf16x8*)((const char*)base + off);
}

// pair-row swizzle for 64B-row bf16 tiles ([rows][32 shorts]): logical (row, cbyte)
// -> byte offset. Per-16-lane slot = ((row&1)*4+lq) ^ ((row>>1)&7): all 8 slots x2 = free.
__device__ __forceinline__ int bpr_off(int row, int cbyte) {
  return ((row >> 1) << 7) + ((((row & 1) << 6) + cbyte) ^ (((row >> 1) & 7) << 4));
}

#define MFMA16(a, b, c) __builtin_amdgcn_mfma_f32_16x16x32_bf16((a), (b), (c), 0, 0, 0)

// ---------------- 4x W [K][N] f32 -> Wt [N][K] bf16, one dispatch ----------------
__global__ void transpose_cast_w4(const float* __restrict__ W0, const float* __restrict__ W1,
                                  const float* __restrict__ W2, const float* __restrict__ W3,
                                  short* __restrict__ T0, short* __restrict__ T1,
                                  short* __restrict__ T2, short* __restrict__ T3) {
  __shared__ float tile[32][33];
  const int z = blockIdx.z;
  const float* W = z == 0 ? W0 : z == 1 ? W1 : z == 2 ? W2 : W3;
  short* Wt = z == 0 ? T0 : z == 1 ? T1 : z == 2 ? T2 : T3;
  const int n0 = blockIdx.x * 32, k0 = blockIdx.y * 32;
  const int tx = threadIdx.x, ty = threadIdx.y;  // 32 x 8
  #pragma unroll
  for (int i = ty; i < 32; i += 8)
    tile[i][tx] = W[(size_t)(k0 + i) * 1024 + n0 + tx];
  __syncthreads();
  #pragma unroll
  for (int i = ty; i < 32; i += 8)
    Wt[(size_t)(n0 + i) * 1024 + k0 + tx] = f2bf(tile[tx][i]);
}

// ---------------- fused QKV GEMM (R6 proven): C = cast_bf16(A_f32) @ Wt^T ----------------
// A staged as raw f32 (XOR-swizzled source); B pair-row swizzled; 2-barrier loop.
// z==0: Q out [B][H][S][HD]*qscale; z==1: K out; z==2: V out [B][H][HD][S].
__global__ __launch_bounds__(256) void gemm_qkv(const float* __restrict__ Aq,
                                                const float* __restrict__ Ak,
                                                const float* __restrict__ Av,
                                                const short* __restrict__ Bq,
                                                const short* __restrict__ Bk,
                                                const short* __restrict__ Bv,
                                                short* __restrict__ Oq,
                                                short* __restrict__ Ok,
                                                short* __restrict__ Ov,
                                                float qscale) {
  __shared__ __align__(16) float Asf[2][128 * 32];   // 32 KB, f32 swizzled rows
  __shared__ __align__(16) short Bs[2][128 * 32];    // 16 KB, pair-row swizzled
  const int z = blockIdx.z;
  const float* A = z == 0 ? Aq : z == 1 ? Ak : Av;
  const short* Bt = z == 0 ? Bq : z == 1 ? Bk : Bv;
  short* outb = z == 0 ? Oq : z == 1 ? Ok : Ov;
  const float oscale = z == 0 ? qscale : 1.0f;

  const int tid = threadIdx.x;
  const int l = tid & 63, w = tid >> 6;
  const int wm = w >> 1, wn = w & 1;
  const int flat = blockIdx.x + (blockIdx.y << 3);
  const int xcd = flat & 7, t = flat >> 3;
  const int row0 = (xcd * 8 + (t & 7)) * 128;
  const int col0 = (t >> 3) * 128;
  const int l15 = l & 15, lq = l >> 4;

  f32x4 acc[4][4] = {};

  auto stageA = [&](int k0, int buf) {
    #pragma unroll
    for (int i = 0; i < 4; i++) {
      const int eoff = w * 4096 + i * 1024 + l * 16;   // byte offset in 16KB tile
      const int row = eoff >> 7;
      const int sc = (eoff & 127) ^ ((row & 7) << 4);  // inverse-swizzled src col
      gload_lds16((const char*)A + (size_t)(row0 + row) * 4096 + (size_t)k0 * 4 + sc,
                  (char*)Asf[buf] + w * 4096 + i * 1024);
    }
  };
  auto stageB = [&](int k0, int buf) {
    #pragma unroll
    for (int i = 0; i < 2; i++) {
      const int o = w * 2048 + i * 1024 + l * 16;      // dest byte in 8KB tile
      const int row2 = o >> 7;
      const int ip = (o & 127) ^ ((row2 & 7) << 4);
      const int row = row2 * 2 + (ip >> 6);
      const int cb = ip & 63;
      gload_lds16((const char*)Bt + ((size_t)(col0 + row) * 1024 + k0) * 2 + cb,
                  (char*)Bs[buf] + o);
    }
  };

  stageA(0, 0);
  stageB(0, 0);

  for (int kt = 0; kt < 32; ++kt) {
    __syncthreads();   // staging of buf kt&1 complete (vmcnt drained at barrier)
    if (kt + 1 < 32) {
      stageA((kt + 1) * 32, (kt + 1) & 1);
      stageB((kt + 1) * 32, (kt + 1) & 1);
    }
    const float* as = Asf[kt & 1];
    const short* bs = Bs[kt & 1];
    bf16x8 af[4], bfv[4];
    #pragma unroll
    for (int mf = 0; mf < 4; mf++) {
      const int R = wm * 64 + mf * 16 + l15;
      const int sw = (R & 7) << 4;
      const f32x4 g0 = *(const f32x4*)((const char*)as + R * 128 + ((lq * 32) ^ sw));
      const f32x4 g1 = *(const f32x4*)((const char*)as + R * 128 + ((lq * 32 + 16) ^ sw));
      const u32x4 uu = {cvtpk(g0[0], g0[1]), cvtpk(g0[2], g0[3]),
                        cvtpk(g1[0], g1[1]), cvtpk(g1[2], g1[3])};
      af[mf] = __builtin_bit_cast(bf16x8, uu);
    }
    #pragma unroll
    for (int nf = 0; nf < 4; nf++)
      bfv[nf] = *(const bf16x8*)((const char*)bs + bpr_off(wn * 64 + nf * 16 + l15, lq * 16));
    #pragma unroll
    for (int mf = 0; mf < 4; mf++)
      #pragma unroll
      for (int nf = 0; nf < 4; nf++)
        acc[mf][nf] = MFMA16(af[mf], bfv[nf], acc[mf][nf]);
  }

  // epilogue: C/D layout col=lane&15, row=(lane>>4)*4+reg
  #pragma unroll
  for (int mf = 0; mf < 4; mf++) {
    #pragma unroll
    for (int nf = 0; nf < 4; nf++) {
      #pragma unroll
      for (int r = 0; r < 4; r++) {
        const int gr = row0 + wm * 64 + mf * 16 + lq * 4 + r;  // m = b*S + s
        const int gc = col0 + wn * 64 + nf * 16 + l15;         // n = h*64 + hd
        const int b = gr >> 11, s = gr & 2047;
        const int h = gc >> 6, hd = gc & 63;
        const float v = acc[mf][nf][r];
        if (z < 2)
          outb[(((size_t)(b * H_ + h)) * S_ + s) * HD_ + hd] = f2bf(v * oscale);
        else
          outb[(((size_t)(b * H_ + h)) * HD_ + hd) * S_ + s] = f2bf(v);
      }
    }
  }
}

// ---------------- O-projection GEMM (R6 proven): f32 out = A_bf16 @ Wot^T + bias ----------------
__global__ __launch_bounds__(256) void gemm_o(const short* __restrict__ A,
                                              const short* __restrict__ Bt,
                                              float* __restrict__ outf,
                                              const float* __restrict__ bias) {
  __shared__ __align__(16) short As[2][128 * 32];
  __shared__ __align__(16) short Bs[2][128 * 32];
  const int tid = threadIdx.x;
  const int l = tid & 63;
  const int w = tid >> 6;
  const int wm = w >> 1, wn = w & 1;
  const int flat = blockIdx.x + (blockIdx.y << 3);
  const int xcd = flat & 7, t = flat >> 3;
  const int row0 = (xcd * 8 + (t & 7)) * 128;
  const int col0 = (t >> 3) * 128;
  const int l15 = l & 15, lq = l >> 4;

  f32x4 acc[4][4] = {};

  auto stage = [&](const short* src, int r0, int k0, short* lds) {
    #pragma unroll
    for (int i = 0; i < 2; i++) {
      const int o = w * 2048 + i * 1024 + l * 16;      // dest byte in 8KB tile
      const int row2 = o >> 7;
      const int ip = (o & 127) ^ ((row2 & 7) << 4);
      const int row = row2 * 2 + (ip >> 6);
      const int cb = ip & 63;
      gload_lds16((const char*)src + ((size_t)(r0 + row) * 1024 + k0) * 2 + cb,
                  (char*)lds + o);
    }
  };

  stage(A, row0, 0, As[0]);
  stage(Bt, col0, 0, Bs[0]);

  for (int kt = 0; kt < 32; ++kt) {
    __syncthreads();
    if (kt + 1 < 32) {
      stage(A, row0, (kt + 1) * 32, As[(kt + 1) & 1]);
      stage(Bt, col0, (kt + 1) * 32, Bs[(kt + 1) & 1]);
    }
    const short* as = As[kt & 1];
    const short* bs = Bs[kt & 1];
    bf16x8 af[4], bfv[4];
    #pragma unroll
    for (int mf = 0; mf < 4; mf++)
      af[mf] = *(const bf16x8*)((const char*)as + bpr_off(wm * 64 + mf * 16 + l15, lq * 16));
    #pragma unroll
    for (int nf = 0; nf < 4; nf++)
      bfv[nf] = *(const bf16x8*)((const char*)bs + bpr_off(wn * 64 + nf * 16 + l15, lq * 16));
    #pragma unroll
    for (int mf = 0; mf < 4; mf++)
      #pragma unroll
      for (int nf = 0; nf < 4; nf++)
        acc[mf][nf] = MFMA16(af[mf], bfv[nf], acc[mf][nf]);
  }

  #pragma unroll
  for (int mf = 0; mf < 4; mf++)
    #pragma unroll
    for (int nf = 0; nf < 4; nf++)
      #pragma unroll
      for (int r = 0; r < 4; r++) {
        const int gr = row0 + wm * 64 + mf * 16 + lq * 4 + r;
        const int gc = col0 + wn * 64 + nf * 16 + l15;
        outf[(size_t)gr * 1024 + gc] = acc[mf][nf][r] + bias[gc];
      }
}

// ---------------- causal flash attention (R5/R10 lpart base, known-pass) ----------------
// Only delta vs the passing R10 text: tree-reassociated row-max (v_max3-friendly, T17).
__global__ __launch_bounds__(256) void attn_kernel(const short* __restrict__ Qh,
                                                   const short* __restrict__ Kh,
                                                   const short* __restrict__ Vtr,
                                                   short* __restrict__ attnout) {
  __shared__ __align__(16) short Ks[2][64 * 64];   // [kv][hd] swizzled
  __shared__ __align__(16) short Vs[2][64 * 64];   // [hd][kv] swizzled
  __shared__ __align__(16) short Ps[4][32 * 64];   // per-wave P[q][kv] swizzled
  const int tid = threadIdx.x, l = tid & 63, w = tid >> 6;
  const int l15 = l & 15, lq = l >> 4;
  const int flat = blockIdx.x;
  const int vid = (flat & 7) * 64 + (flat >> 3);   // 8 bh per XCD (K+V working set ~4MB = L2)
  const int bh = vid >> 3, pairx = vid & 7;
  const int b = bh >> 4, h = bh & 15;
  const size_t base = (size_t)bh * (S_ * HD_);
  const short* Qp = Qh + base;
  const short* Kp = Kh + base;
  const short* Vp = Vtr + base;   // [64][2048]
  short* Pw = (short*)Ps[w];

  for (int pass = 0; pass < 2; ++pass) {
    const int qt = pass ? 15 - pairx : pairx;      // diagonal pairing: total work uniform
    const int q0 = qt * 128;
    const int qw = q0 + w * 32;
    const int nkt = (q0 >> 6) + 2;

    // Q B-fragments (q already pre-scaled by 0.125*log2e in the Q projection)
    bf16x8 qf[2][2];
    #pragma unroll
    for (int qh = 0; qh < 2; qh++)
      #pragma unroll
      for (int ks = 0; ks < 2; ks++)
        qf[qh][ks] = *(const bf16x8*)(Qp + (size_t)(qw + qh * 16 + l15) * 64 + ks * 32 + lq * 8);

    f32x4 oacc[4][2] = {};          // [hd-frag][q-half]: O^T, rows hd, cols q=l15
    float mrow[2] = {-1e30f, -1e30f};
    float lpart[2] = {0.f, 0.f};    // per-lane partial row-sum (reduced only at epilogue)

    auto stage = [&](int kt, int bf) {
      const int k0s = kt << 6;
      #pragma unroll
      for (int i = 0; i < 2; i++) {
        const int o = w * 2048 + i * 1024 + l * 16;          // byte offset in 8KB tile
        const int sw = o ^ (((o >> 7) & 7) << 4);            // inverse-swizzled source (rule 21)
        gload_lds16((const char*)Kp + (size_t)k0s * 128 + sw, (char*)Ks[bf] + o);
        gload_lds16(Vp + (size_t)(o >> 7) * S_ + k0s + ((sw & 127) >> 1), (char*)Vs[bf] + o);
      }
    };

    stage(0, 0);
    __syncthreads();

    for (int kt = 0; kt < nkt; ++kt) {
      const int cur = kt & 1;
      if (kt + 1 < nkt) stage(kt + 1, cur ^ 1);   // prefetch in flight across compute
      const int k0 = kt << 6;

      if (k0 <= qw + 31) {                         // wave-level fully-masked-tile skip
        // --- QK^T swapped: sacc[qh][mf] holds S^T[kv=16mf+4lq+r][q=16qh+l15] ---
        f32x4 sacc[2][4] = {};
        __builtin_amdgcn_s_setprio(1);
        #pragma unroll
        for (int ks = 0; ks < 2; ks++) {
          #pragma unroll
          for (int mf = 0; mf < 4; mf++) {
            const bf16x8 kf = ldsw8(Ks[cur], mf * 16 + l15, ks * 64 + lq * 16);
            #pragma unroll
            for (int qh = 0; qh < 2; qh++)
              sacc[qh][mf] = MFMA16(kf, qf[qh][ks], sacc[qh][mf]);
          }
        }
        __builtin_amdgcn_s_setprio(0);

        // causal mask — only diagonal tiles
        if (k0 + 63 > qw) {
          #pragma unroll
          for (int qh = 0; qh < 2; qh++) {
            const int qg = qw + qh * 16 + l15 - lq * 4;   // kv>q  <=>  k0+16mf+r > qg
            #pragma unroll
            for (int mf = 0; mf < 4; mf++)
              #pragma unroll
              for (int r = 0; r < 4; r++)
                if (k0 + mf * 16 + r > qg) sacc[qh][mf][r] = -1e30f;
          }
        }

        // per-lane local max: balanced tree (v_max3-fusible), no shfl unless rescale fires
        float mxl[2];
        #pragma unroll
        for (int qh = 0; qh < 2; qh++) {
          float t0 = fmaxf(fmaxf(sacc[qh][0][0], sacc[qh][0][1]),
                           fmaxf(sacc[qh][0][2], sacc[qh][0][3]));
          float t1 = fmaxf(fmaxf(sacc[qh][1][0], sacc[qh][1][1]),
                           fmaxf(sacc[qh][1][2], sacc[qh][1][3]));
          float t2 = fmaxf(fmaxf(sacc[qh][2][0], sacc[qh][2][1]),
                           fmaxf(sacc[qh][2][2], sacc[qh][2][3]));
          float t3 = fmaxf(fmaxf(sacc[qh][3][0], sacc[qh][3][1]),
                           fmaxf(sacc[qh][3][2], sacc[qh][3][3]));
          mxl[qh] = fmaxf(fmaxf(t0, t1), fmaxf(t2, t3));
        }

        // defer-max (T13, THR=8 in log2 domain); lane-max trigger == row-max trigger
        const bool need = (mxl[0] > mrow[0] + 8.f) || (mxl[1] > mrow[1] + 8.f);
        if (__any(need)) {
          #pragma unroll
          for (int qh = 0; qh < 2; qh++) {
            float m = fmaxf(mxl[qh], __shfl_xor(mxl[qh], 16));
            m = fmaxf(m, __shfl_xor(m, 32));
            const float mn = fmaxf(mrow[qh], m);
            const float fac = __builtin_amdgcn_exp2f(mrow[qh] - mn);
            mrow[qh] = mn;
            lpart[qh] *= fac;
            #pragma unroll
            for (int mf = 0; mf < 4; mf++) oacc[mf][qh] *= fac;
          }
        }

        // exp2, per-lane sum, HW-packed P -> per-wave LDS (8 x ds_write_b64)
        #pragma unroll
        for (int qh = 0; qh < 2; qh++) {
          float rs = 0.f;
          const int row = qh * 16 + l15;
          #pragma unroll
          for (int mf = 0; mf < 4; mf++) {
            f32x4 p;
            #pragma unroll
            for (int r = 0; r < 4; r++) {
              const float e = __builtin_amdgcn_exp2f(sacc[qh][mf][r] - mrow[qh]);
              p[r] = e;
              rs += e;
            }
            const int off = (row * 128 + mf * 32 + lq * 8) ^ ((row & 7) << 4);
            *(uint2*)((char*)Pw + off) = make_uint2(cvtpk(p[0], p[1]), cvtpk(p[2], p[3]));
          }
          lpart[qh] += rs;
        }

        asm volatile("s_waitcnt lgkmcnt(0)" ::: "memory");
        __builtin_amdgcn_sched_barrier(0);

        // --- PV swapped: oacc[mf][qh] += V^T-frag x P^T-frag ---
        __builtin_amdgcn_s_setprio(1);
        #pragma unroll
        for (int ks = 0; ks < 2; ks++) {
          bf16x8 pb[2];
          #pragma unroll
          for (int qh = 0; qh < 2; qh++) {
            const int row = qh * 16 + l15;
            const int off = (row * 128 + ks * 64 + lq * 16) ^ ((row & 7) << 4);
            pb[qh] = *(const bf16x8*)((const char*)Pw + off);
          }
          #pragma unroll
          for (int mf = 0; mf < 4; mf++) {
            const bf16x8 vf = ldsw8(Vs[cur], mf * 16 + l15, ks * 64 + lq * 16);
            #pragma unroll
            for (int qh = 0; qh < 2; qh++)
              oacc[mf][qh] = MFMA16(vf, pb[qh], oacc[mf][qh]);
          }
        }
        __builtin_amdgcn_s_setprio(0);
      }
      __syncthreads();   // prefetch drained (vmcnt) + all waves done with buf cur
    }

    // epilogue: O^T rows hd=16mf+4lq+r, col q=16qh+l15 -> attnout [B][S][H*HD]
    #pragma unroll
    for (int qh = 0; qh < 2; qh++) {
      float lr = lpart[qh];
      lr += __shfl_xor(lr, 16);
      lr += __shfl_xor(lr, 32);
      const float rinv = __builtin_amdgcn_rcpf(lr);
      const int q = qw + qh * 16 + l15;
      #pragma unroll
      for (int mf = 0; mf < 4; mf++) {
        const f32x4 o = oacc[mf][qh];
        const uint2 u = make_uint2(cvtpk(o[0] * rinv, o[1] * rinv),
                                   cvtpk(o[2] * rinv, o[3] * rinv));
        *(uint2*)(attnout + ((size_t)b * S_ + q) * (H_ * HD_) + h * 64 + mf * 16 + lq * 4) = u;
      }
    }
  }
}

extern "C" void kernel_launch(void* const* d_in, const int* in_sizes, int n_in,
                              void* d_out, int out_size, void* d_ws, size_t ws_size,
                              hipStream_t stream) {
  const float* query = (const float*)d_in[0];
  const float* key_  = (const float*)d_in[1];
  const float* value = (const float*)d_in[2];
  // d_in[3] = causal mask — implied analytically
  const float* Wq = (const float*)d_in[4];
  const float* Wk = (const float*)d_in[5];
  const float* Wv = (const float*)d_in[6];
  const float* Wo = (const float*)d_in[7];
  const float* bo = (const float*)d_in[8];
  float* out = (float*)d_out;

  char* ws = (char*)d_ws;
  const size_t MB = (size_t)1 << 20;
  short* Xbuf = (short*)(ws);             // 16 MB: attn output
  short* Wqt  = (short*)(ws + 16 * MB);
  short* Wkt  = (short*)(ws + 18 * MB);
  short* Wvt  = (short*)(ws + 20 * MB);
  short* Wot  = (short*)(ws + 22 * MB);
  short* Qh   = (short*)(ws + 24 * MB);   // 16 MB [B][H][S][HD], pre-scaled by 0.125*log2e
  short* Kh   = (short*)(ws + 40 * MB);   // 16 MB [B][H][S][HD]
  short* Vt   = (short*)(ws + 56 * MB);   // 16 MB [B][H][HD][S]   (total 72 MB)

  const dim3 tb(32, 8);
  const dim3 tg4(32, 32, 4);
  const float QSCALE = 0.125f * 1.4426950408889634f;  // fold 1/sqrt(HD) * log2(e) into Q

  transpose_cast_w4<<<tg4, tb, 0, stream>>>(Wq, Wk, Wv, Wo, Wqt, Wkt, Wvt, Wot);

  gemm_qkv<<<dim3(8, 64, 3), 256, 0, stream>>>(query, key_, value, Wqt, Wkt, Wvt,
                                               Qh, Kh, Vt, QSCALE);

  attn_kernel<<<dim3(512), 256, 0, stream>>>(Qh, Kh, Vt, Xbuf);

  gemm_o<<<dim3(8, 64), 256, 0, stream>>>(Xbuf, Wot, out, bo);
}